// Round 1
// baseline (1578.817 us; speedup 1.0000x reference)
//
#include <hip/hip_runtime.h>
#include <hip/hip_bf16.h>
#include <stdint.h>

typedef __attribute__((ext_vector_type(8))) short short8;
typedef __attribute__((ext_vector_type(8))) unsigned short ushort8;
typedef __attribute__((ext_vector_type(4))) float f32x4;

#define DEVFN static __device__ __forceinline__

#define NNODES 50000
#define MPAD   50048
#define EDGES  1600000

DEVFN float bf2f(unsigned short u){
  unsigned int v = ((unsigned int)u) << 16;
  return __builtin_bit_cast(float, v);
}
DEVFN unsigned short f2bf(float f){
  unsigned int u = __builtin_bit_cast(unsigned int, f);
  u += 0x7FFFu + ((u >> 16) & 1u);
  return (unsigned short)(u >> 16);
}

typedef __attribute__((address_space(1))) const unsigned int gu32_t;
typedef __attribute__((address_space(3))) unsigned int lu32_t;
DEVFN void async16(const void* g, void* l){
  __builtin_amdgcn_global_load_lds((gu32_t*)g, (lu32_t*)l, 16, 0, 0);
}

// ---------------- cast x [50000][2000] f32 -> [50048][2048] bf16 (zero pad) ----
__global__ void cast_x_kernel(const float* __restrict__ x, unsigned short* __restrict__ xb){
  long i = (long)blockIdx.x * blockDim.x + threadIdx.x;
  const long total = (long)MPAD * 2048 / 8;
  const long stride = (long)gridDim.x * blockDim.x;
  for (; i < total; i += stride){
    long e0 = i * 8;
    int row = (int)(e0 >> 11);
    int col = (int)(e0 & 2047);
    ushort8 v = {0,0,0,0,0,0,0,0};
    if (row < NNODES && col < 2000){
      const float* s = x + (long)row * 2000 + col;
      #pragma unroll
      for (int j = 0; j < 8; j++) v[j] = f2bf(s[j]);
    }
    *(ushort8*)(xb + e0) = v;
  }
}

// ---------------- transpose-cast W [K][N] f32 -> dst[(rowOff+n)][Kpad] bf16 ----
__global__ void transpose_cast(const float* __restrict__ src, unsigned short* __restrict__ dst,
                               int K, int Ncols, int Kpad, int rowOff){
  long i = (long)blockIdx.x * blockDim.x + threadIdx.x;
  long total = (long)Ncols * Kpad;
  long stride = (long)gridDim.x * blockDim.x;
  for (; i < total; i += stride){
    int n = (int)(i / Kpad);
    int k = (int)(i - (long)n * Kpad);
    unsigned short v = 0;
    if (k < K) v = f2bf(src[(long)k * Ncols + n]);
    dst[(long)(rowOff + n) * Kpad + k] = v;
  }
}

// ---------------- CSR build ----------------
__global__ void hist_kernel(const int* __restrict__ rows, int* __restrict__ counts){
  int i = blockIdx.x * blockDim.x + threadIdx.x;
  int stride = gridDim.x * blockDim.x;
  for (; i < EDGES; i += stride) atomicAdd(&counts[rows[i]], 1);
}

__global__ void scan_kernel(const int* __restrict__ counts, int* __restrict__ offs){
  __shared__ int part[1024];
  const int n = NNODES;
  const int chunk = 49; // 49*1024 = 50176 >= 50001
  int t = threadIdx.x;
  int base = t * chunk;
  int s = 0;
  for (int i = 0; i < chunk; i++){ int idx = base + i; if (idx < n) s += counts[idx]; }
  part[t] = s; __syncthreads();
  for (int off = 1; off < 1024; off <<= 1){
    int v = 0;
    if (t >= off) v = part[t - off];
    __syncthreads();
    part[t] += v;
    __syncthreads();
  }
  int run = t ? part[t - 1] : 0;
  for (int i = 0; i < chunk; i++){
    int idx = base + i;
    if (idx <= n){
      offs[idx] = run;
      if (idx < n) run += counts[idx];
    }
  }
}

__global__ void fill_kernel(const int* __restrict__ rows, const int* __restrict__ cols,
                            const float* __restrict__ vals, int* __restrict__ cursor,
                            int* __restrict__ ecol, float* __restrict__ eval){
  int i = blockIdx.x * blockDim.x + threadIdx.x;
  int stride = gridDim.x * blockDim.x;
  for (; i < EDGES; i += stride){
    int r = rows[i];
    int p = atomicAdd(&cursor[r], 1);
    ecol[p] = cols[i];
    eval[p] = vals[i];
  }
}

// ---------------- aggregate: wave per node, 8 cols/lane ----------------
__launch_bounds__(256)
__global__ void aggregate_kernel(const int* __restrict__ offs, const int* __restrict__ ecol,
                                 const float* __restrict__ eval, const unsigned short* __restrict__ h,
                                 float* __restrict__ agg){
  int wv = threadIdx.x >> 6, lane = threadIdx.x & 63;
  int node = blockIdx.x * 4 + wv;
  int beg = offs[node], end = offs[node + 1];
  float acc[8];
  #pragma unroll
  for (int j = 0; j < 8; j++) acc[j] = 0.f;
  const unsigned short* hp = h + lane * 8;
  for (int i = beg; i < end; i++){
    int c = ecol[i];
    float v = eval[i];
    ushort8 u = *(const ushort8*)(hp + (long)c * 512);
    #pragma unroll
    for (int j = 0; j < 8; j++) acc[j] = fmaf(v, bf2f(u[j]), acc[j]);
  }
  float* op = agg + (long)node * 512 + lane * 8;
  f32x4 lo = {acc[0], acc[1], acc[2], acc[3]};
  f32x4 hi = {acc[4], acc[5], acc[6], acc[7]};
  *(f32x4*)op = lo;
  *(f32x4*)(op + 4) = hi;
}

// ---------------- BN column stats ----------------
template<int C>
__global__ void bn_stats_kernel(const float* __restrict__ z, double* __restrict__ dsum, double* __restrict__ dsq){
  constexpr int PC = C / 256;
  int t = threadIdx.x;
  float s[PC], q[PC];
  #pragma unroll
  for (int p = 0; p < PC; p++){ s[p] = 0.f; q[p] = 0.f; }
  for (int r = blockIdx.x; r < NNODES; r += gridDim.x){
    const float* zr = z + (long)r * C;
    #pragma unroll
    for (int p = 0; p < PC; p++){
      float v = zr[t + p * 256];
      s[p] += v; q[p] += v * v;
    }
  }
  #pragma unroll
  for (int p = 0; p < PC; p++){
    atomicAdd(&dsum[t + p * 256], (double)s[p]);
    atomicAdd(&dsq[t + p * 256], (double)q[p]);
  }
}

__global__ void bn_finalize_kernel(const double* __restrict__ dsum, const double* __restrict__ dsq,
                                   const float* __restrict__ gamma, const float* __restrict__ beta,
                                   float* __restrict__ scale, float* __restrict__ shift, int C){
  int c = blockIdx.x * blockDim.x + threadIdx.x;
  if (c < C){
    double m = dsum[c] / (double)NNODES;
    double var = dsq[c] / (double)NNODES - m * m;
    float rs = (float)(1.0 / sqrt(var + 1e-5));
    float sc = rs * gamma[c];
    scale[c] = sc;
    shift[c] = beta[c] - (float)m * sc;
  }
}

// ---------------- fused BN + softplus -> bf16 ----------------
template<int C>
__global__ void bn_softplus_kernel(const float* __restrict__ z, const float* __restrict__ scale,
                                   const float* __restrict__ shift, unsigned short* __restrict__ out,
                                   int rowsTotal){
  long i = (long)blockIdx.x * blockDim.x + threadIdx.x;
  long total = (long)rowsTotal * C / 8;
  long stride = (long)gridDim.x * blockDim.x;
  for (; i < total; i += stride){
    long e0 = i * 8;
    int c0 = (int)(e0 & (C - 1));
    const float* zp = z + e0;
    ushort8 o;
    #pragma unroll
    for (int j = 0; j < 8; j++){
      float y = fmaf(zp[j], scale[c0 + j], shift[c0 + j]);
      float sp = (y > 15.f) ? y : log1pf(__expf(y));
      o[j] = f2bf(sp);
    }
    *(ushort8*)(out + e0) = o;
  }
}

// ---------------- bf16 MFMA GEMM: C[M][N] = A[M][K] * B[N][K]^T (+bias) -------
// 128x128 tile, BK=64, 4 waves (2x2 of 64x64), 16x16x32 bf16 MFMA.
// LDS linear dest for global_load_lds; XOR swizzle via pre-swizzled global src.
template<int EPI>
__launch_bounds__(256, 2)
__global__ void gemm_kernel(const unsigned short* __restrict__ A, const unsigned short* __restrict__ B,
                            const float* __restrict__ bias, const float* __restrict__ bias2,
                            void* __restrict__ Cout, int N, int K){
  __shared__ unsigned short As[128 * 64];
  __shared__ unsigned short Bs[128 * 64];
  const int t = threadIdx.x;
  const int lane = t & 63;
  const int w = t >> 6;
  const long row0 = (long)blockIdx.x * 128;
  const int col0 = blockIdx.y * 128;

  const int rI = lane >> 3;            // row within 8-row chunk (== row&7)
  const int sI = (lane & 7) ^ rI;      // pre-swizzled source 16B-slot

  f32x4 acc[4][4];
  #pragma unroll
  for (int i = 0; i < 4; i++)
    #pragma unroll
    for (int j = 0; j < 4; j++){
      f32x4 z = {0.f, 0.f, 0.f, 0.f};
      acc[i][j] = z;
    }

  const int wm = (w >> 1) * 64;
  const int wn = (w & 1) * 64;
  const int nk = K >> 6;

  const unsigned short* Abase = A + row0 * K + sI * 8;
  const unsigned short* Bbase = B + (long)col0 * K + sI * 8;

  for (int kt = 0; kt < nk; ++kt){
    const int kb = kt * 64;
    #pragma unroll
    for (int i = 0; i < 4; i++){
      int c = i * 4 + w;
      int rowt = c * 8 + rI;
      async16(Abase + (long)rowt * K + kb, As + c * 512);
      async16(Bbase + (long)rowt * K + kb, Bs + c * 512);
    }
    __syncthreads();
    #pragma unroll
    for (int ks = 0; ks < 2; ++ks){
      short8 af[4], bfr[4];
      #pragma unroll
      for (int f = 0; f < 4; f++){
        int ra = wm + f * 16 + (lane & 15);
        int sa = (ks * 4 + (lane >> 4)) ^ (ra & 7);
        af[f] = *(const short8*)(As + ra * 64 + sa * 8);
        int rb = wn + f * 16 + (lane & 15);
        int sb = (ks * 4 + (lane >> 4)) ^ (rb & 7);
        bfr[f] = *(const short8*)(Bs + rb * 64 + sb * 8);
      }
      #pragma unroll
      for (int fm = 0; fm < 4; fm++)
        #pragma unroll
        for (int fn = 0; fn < 4; fn++)
          acc[fm][fn] = __builtin_amdgcn_mfma_f32_16x16x32_bf16(af[fm], bfr[fn], acc[fm][fn], 0, 0, 0);
    }
    __syncthreads();
  }

  // epilogue: C/D layout col=lane&15, row=(lane>>4)*4+reg
  #pragma unroll
  for (int fm = 0; fm < 4; fm++){
    #pragma unroll
    for (int fn = 0; fn < 4; fn++){
      #pragma unroll
      for (int j = 0; j < 4; j++){
        long r = row0 + wm + fm * 16 + ((lane >> 4) * 4 + j);
        int cc = col0 + wn + fn * 16 + (lane & 15);
        float v = acc[fm][fn][j];
        if (EPI == 0){
          v += bias[cc];
          ((unsigned short*)Cout)[r * N + cc] = f2bf(v);
        } else if (EPI == 1){
          v += bias[cc];
          ((float*)Cout)[r * N + cc] = v;
        } else {
          if (r < NNODES){
            float bb = (cc < 64) ? bias[cc] : bias2[cc - 64];
            long o = (cc < 64) ? ((long)r * 64 + cc) : ((long)64 * NNODES + (long)r * 64 + (cc - 64));
            ((float*)Cout)[o] = v + bb;
          }
        }
      }
    }
  }
}

// ---------------- host ----------------
extern "C" void kernel_launch(void* const* d_in, const int* in_sizes, int n_in,
                              void* d_out, int out_size, void* d_ws, size_t ws_size,
                              hipStream_t stream){
  const float* x        = (const float*)d_in[0];
  const int*   adj_rows = (const int*)d_in[1];
  const int*   adj_cols = (const int*)d_in[2];
  const float* adj_vals = (const float*)d_in[3];
  const float* Wg       = (const float*)d_in[4];
  const float* bg       = (const float*)d_in[5];
  const float* W1       = (const float*)d_in[6];
  const float* b1       = (const float*)d_in[7];
  const float* W21      = (const float*)d_in[8];
  const float* b21      = (const float*)d_in[9];
  const float* W22      = (const float*)d_in[10];
  const float* b22      = (const float*)d_in[11];
  const float* gamma0   = (const float*)d_in[12];
  const float* beta0    = (const float*)d_in[13];
  const float* gamma1   = (const float*)d_in[14];
  const float* beta1    = (const float*)d_in[15];

  char* ws = (char*)d_ws;
  // arena
  unsigned short* xb  = (unsigned short*)(ws + 0);                 // 205,000,704 B
  float* agg          = (float*)(ws + 0);                          // reuse after GEMM1
  float* z1           = (float*)(ws + 102498304);
  unsigned short* h1  = (unsigned short*)(ws + 153747456);
  size_t o = 205000704;
  unsigned short* WgT = (unsigned short*)(ws + o); o += 2097152;
  unsigned short* W1T = (unsigned short*)(ws + o); o += 262144;
  unsigned short* WcT = (unsigned short*)(ws + o); o += 65536;
  unsigned short* hbf = (unsigned short*)(ws + o); o += 51249152;
  unsigned short* h0  = (unsigned short*)(ws + o); o += 51249152;
  int* counts = (int*)(ws + o); o += 200192;
  int* offs   = (int*)(ws + o); o += 200192;
  int* cursor = (int*)(ws + o); o += 200192;
  int* ecol   = (int*)(ws + o); o += 6400000;
  float* eval = (float*)(ws + o); o += 6400000;
  double* dsum0 = (double*)(ws + o); o += 4096;
  double* dsq0  = (double*)(ws + o); o += 4096;
  double* dsum1 = (double*)(ws + o); o += 2048;
  double* dsq1  = (double*)(ws + o); o += 2048;
  float* scale0 = (float*)(ws + o); o += 2048;
  float* shift0 = (float*)(ws + o); o += 2048;
  float* scale1 = (float*)(ws + o); o += 1024;
  float* shift1 = (float*)(ws + o); o += 1024;

  hipMemsetAsync(counts, 0, NNODES * sizeof(int), stream);
  hipMemsetAsync(dsum0, 0, 12288, stream);   // dsum0,dsq0,dsum1,dsq1 contiguous

  cast_x_kernel<<<2048, 256, 0, stream>>>(x, xb);
  transpose_cast<<<512, 256, 0, stream>>>(Wg, WgT, 2000, 512, 2048, 0);
  transpose_cast<<<128, 256, 0, stream>>>(W1, W1T, 512, 256, 512, 0);
  transpose_cast<<<64, 256, 0, stream>>>(W21, WcT, 256, 64, 256, 0);
  transpose_cast<<<64, 256, 0, stream>>>(W22, WcT, 256, 64, 256, 64);

  hist_kernel<<<2048, 256, 0, stream>>>(adj_rows, counts);
  scan_kernel<<<1, 1024, 0, stream>>>(counts, offs);
  hipMemcpyAsync(cursor, offs, NNODES * sizeof(int), hipMemcpyDeviceToDevice, stream);
  fill_kernel<<<2048, 256, 0, stream>>>(adj_rows, adj_cols, adj_vals, cursor, ecol, eval);

  gemm_kernel<0><<<dim3(MPAD / 128, 4), 256, 0, stream>>>(xb, WgT, bg, nullptr, hbf, 512, 2048);

  aggregate_kernel<<<NNODES / 4, 256, 0, stream>>>(offs, ecol, eval, hbf, agg);

  bn_stats_kernel<512><<<512, 256, 0, stream>>>(agg, dsum0, dsq0);
  bn_finalize_kernel<<<2, 256, 0, stream>>>(dsum0, dsq0, gamma0, beta0, scale0, shift0, 512);
  bn_softplus_kernel<512><<<2048, 256, 0, stream>>>(agg, scale0, shift0, h0, MPAD);

  gemm_kernel<1><<<dim3(MPAD / 128, 2), 256, 0, stream>>>(h0, W1T, b1, nullptr, z1, 256, 512);

  bn_stats_kernel<256><<<512, 256, 0, stream>>>(z1, dsum1, dsq1);
  bn_finalize_kernel<<<1, 256, 0, stream>>>(dsum1, dsq1, gamma1, beta1, scale1, shift1, 256);
  bn_softplus_kernel<256><<<1024, 256, 0, stream>>>(z1, scale1, shift1, h1, MPAD);

  gemm_kernel<2><<<dim3(MPAD / 128, 1), 256, 0, stream>>>(h1, WcT, b21, b22, (float*)d_out, 128, 256);

  (void)in_sizes; (void)n_in; (void)out_size; (void)ws_size;
}

// Round 2
// 1319.142 us; speedup vs baseline: 1.1969x; 1.1969x over previous
//
#include <hip/hip_runtime.h>
#include <hip/hip_bf16.h>
#include <stdint.h>

typedef __attribute__((ext_vector_type(8))) short short8;
typedef __attribute__((ext_vector_type(8))) unsigned short ushort8;
typedef __attribute__((ext_vector_type(4))) float f32x4;

#define DEVFN static __device__ __forceinline__

#define NNODES 50000
#define MPAD   50048
#define EDGES  1600000
#define SCHUNK 196   // 256 blocks * 196 = 50176 >= 50001

DEVFN float bf2f(unsigned short u){
  unsigned int v = ((unsigned int)u) << 16;
  return __builtin_bit_cast(float, v);
}
DEVFN unsigned short f2bf(float f){
  unsigned int u = __builtin_bit_cast(unsigned int, f);
  u += 0x7FFFu + ((u >> 16) & 1u);
  return (unsigned short)(u >> 16);
}

typedef __attribute__((address_space(1))) const unsigned int gu32_t;
typedef __attribute__((address_space(3))) unsigned int lu32_t;
DEVFN void async16(const void* g, void* l){
  __builtin_amdgcn_global_load_lds((gu32_t*)g, (lu32_t*)l, 16, 0, 0);
}

// ---------------- cast x [50000][2000] f32 -> [50048][2048] bf16 (zero pad) ----
__global__ void cast_x_kernel(const float* __restrict__ x, unsigned short* __restrict__ xb){
  long i = (long)blockIdx.x * blockDim.x + threadIdx.x;
  const long total = (long)MPAD * 2048 / 8;
  const long stride = (long)gridDim.x * blockDim.x;
  for (; i < total; i += stride){
    long e0 = i * 8;
    int row = (int)(e0 >> 11);
    int col = (int)(e0 & 2047);
    ushort8 v = {0,0,0,0,0,0,0,0};
    if (row < NNODES && col < 2000){
      const float* s = x + (long)row * 2000 + col;
      #pragma unroll
      for (int j = 0; j < 8; j++) v[j] = f2bf(s[j]);
    }
    *(ushort8*)(xb + e0) = v;
  }
}

// ---------------- fused weight transpose-cast (all pow-2 strides) -------------
// Wg[2000][512] -> WgT[512][2048]; W1[512][256] -> W1T[256][512];
// W21[256][64] -> WcT[0..63][256]; W22[256][64] -> WcT[64..127][256]
__global__ void prep_weights(const float* __restrict__ Wg, const float* __restrict__ W1,
                             const float* __restrict__ W21, const float* __restrict__ W22,
                             unsigned short* __restrict__ WgT, unsigned short* __restrict__ W1T,
                             unsigned short* __restrict__ WcT){
  const int n0 = 512 * 2048;
  const int n1 = 256 * 512;
  const int n2 = 64 * 256;
  const int total = n0 + n1 + 2 * n2;
  int i = blockIdx.x * blockDim.x + threadIdx.x;
  int stride = gridDim.x * blockDim.x;
  for (; i < total; i += stride){
    if (i < n0){
      int n = i >> 11, k = i & 2047;
      WgT[i] = (k < 2000) ? f2bf(Wg[(long)k * 512 + n]) : (unsigned short)0;
    } else if (i < n0 + n1){
      int j = i - n0;
      int n = j >> 9, k = j & 511;
      W1T[j] = f2bf(W1[(long)k * 256 + n]);
    } else if (i < n0 + n1 + n2){
      int j = i - n0 - n1;
      int n = j >> 8, k = j & 255;
      WcT[j] = f2bf(W21[(long)k * 64 + n]);
    } else {
      int j = i - n0 - n1 - n2;
      int n = j >> 8, k = j & 255;
      WcT[n2 + j] = f2bf(W22[(long)k * 64 + n]);
    }
  }
}

// ---------------- CSR build ----------------
__global__ void hist_kernel(const int* __restrict__ rows, int* __restrict__ counts){
  int i = blockIdx.x * blockDim.x + threadIdx.x;
  int stride = gridDim.x * blockDim.x;
  for (; i < EDGES; i += stride) atomicAdd(&counts[rows[i]], 1);
}

// per-chunk sums (coalesced)
__global__ void scan_partials(const int* __restrict__ counts, int* __restrict__ part){
  __shared__ int red[256];
  int b = blockIdx.x, t = threadIdx.x;
  int idx = b * SCHUNK + t;
  int s = (t < SCHUNK && idx < NNODES) ? counts[idx] : 0;
  red[t] = s; __syncthreads();
  for (int o = 128; o; o >>= 1){
    if (t < o) red[t] += red[t + o];
    __syncthreads();
  }
  if (!t) part[b] = red[0];
}

// exclusive scan of the 256 partials
__global__ void scan_scan(int* __restrict__ part){
  __shared__ int s[256];
  int t = threadIdx.x;
  s[t] = part[t]; __syncthreads();
  for (int o = 1; o < 256; o <<= 1){
    int v = (t >= o) ? s[t - o] : 0;
    __syncthreads();
    s[t] += v;
    __syncthreads();
  }
  part[t] = t ? s[t - 1] : 0;
}

// expand to per-node offsets; writes offs AND cursor (init for fill)
__global__ void scan_expand(const int* __restrict__ counts, const int* __restrict__ part,
                            int* __restrict__ offs, int* __restrict__ cursor){
  __shared__ int s[256];
  int b = blockIdx.x, t = threadIdx.x;
  int idx = b * SCHUNK + t;
  int val = (t < SCHUNK && idx < NNODES) ? counts[idx] : 0;
  s[t] = val; __syncthreads();
  for (int o = 1; o < 256; o <<= 1){
    int v = (t >= o) ? s[t - o] : 0;
    __syncthreads();
    s[t] += v;
    __syncthreads();
  }
  if (t < SCHUNK && idx <= NNODES){
    int excl = s[t] - val + part[b];
    if (idx < NNODES){ offs[idx] = excl; cursor[idx] = excl; }
    else offs[NNODES] = excl;
  }
}

// scatter edges into CSR order; pack (val,col) into one 8B word
__global__ void fill_kernel(const int* __restrict__ rows, const int* __restrict__ cols,
                            const float* __restrict__ vals, int* __restrict__ cursor,
                            unsigned long long* __restrict__ ep){
  int i = blockIdx.x * blockDim.x + threadIdx.x;
  int stride = gridDim.x * blockDim.x;
  for (; i < EDGES; i += stride){
    int r = rows[i];
    int p = atomicAdd(&cursor[r], 1);
    unsigned int vb = __builtin_bit_cast(unsigned int, vals[i]);
    ep[p] = ((unsigned long long)vb << 32) | (unsigned int)cols[i];
  }
}

// ---------------- aggregate: wave per node, 8 cols/lane, 4-deep MLP ----------
__launch_bounds__(256)
__global__ void aggregate_kernel(const int* __restrict__ offs, const unsigned long long* __restrict__ ep,
                                 const unsigned short* __restrict__ h, float* __restrict__ agg){
  int wv = threadIdx.x >> 6, lane = threadIdx.x & 63;
  int node = blockIdx.x * 4 + wv;
  int beg = offs[node], end = offs[node + 1];
  float acc[8];
  #pragma unroll
  for (int j = 0; j < 8; j++) acc[j] = 0.f;
  const unsigned short* hp = h + lane * 8;
  int i = beg;
  for (; i + 4 <= end; i += 4){
    unsigned long long e0 = ep[i], e1 = ep[i + 1], e2 = ep[i + 2], e3 = ep[i + 3];
    const ushort8 u0 = *(const ushort8*)(hp + (long)(unsigned int)e0 * 512);
    const ushort8 u1 = *(const ushort8*)(hp + (long)(unsigned int)e1 * 512);
    const ushort8 u2 = *(const ushort8*)(hp + (long)(unsigned int)e2 * 512);
    const ushort8 u3 = *(const ushort8*)(hp + (long)(unsigned int)e3 * 512);
    float v0 = __builtin_bit_cast(float, (unsigned int)(e0 >> 32));
    float v1 = __builtin_bit_cast(float, (unsigned int)(e1 >> 32));
    float v2 = __builtin_bit_cast(float, (unsigned int)(e2 >> 32));
    float v3 = __builtin_bit_cast(float, (unsigned int)(e3 >> 32));
    #pragma unroll
    for (int j = 0; j < 8; j++){
      acc[j] = fmaf(v0, bf2f(u0[j]), acc[j]);
      acc[j] = fmaf(v1, bf2f(u1[j]), acc[j]);
      acc[j] = fmaf(v2, bf2f(u2[j]), acc[j]);
      acc[j] = fmaf(v3, bf2f(u3[j]), acc[j]);
    }
  }
  for (; i < end; i++){
    unsigned long long e = ep[i];
    const ushort8 u = *(const ushort8*)(hp + (long)(unsigned int)e * 512);
    float v = __builtin_bit_cast(float, (unsigned int)(e >> 32));
    #pragma unroll
    for (int j = 0; j < 8; j++) acc[j] = fmaf(v, bf2f(u[j]), acc[j]);
  }
  float* op = agg + (long)node * 512 + lane * 8;
  f32x4 lo = {acc[0], acc[1], acc[2], acc[3]};
  f32x4 hi = {acc[4], acc[5], acc[6], acc[7]};
  *(f32x4*)op = lo;
  *(f32x4*)(op + 4) = hi;
}

// ---------------- BN column stats ----------------
template<int C>
__global__ void bn_stats_kernel(const float* __restrict__ z, double* __restrict__ dsum, double* __restrict__ dsq){
  constexpr int PC = C / 256;
  int t = threadIdx.x;
  float s[PC], q[PC];
  #pragma unroll
  for (int p = 0; p < PC; p++){ s[p] = 0.f; q[p] = 0.f; }
  for (int r = blockIdx.x; r < NNODES; r += gridDim.x){
    const float* zr = z + (long)r * C;
    #pragma unroll
    for (int p = 0; p < PC; p++){
      float v = zr[t + p * 256];
      s[p] += v; q[p] += v * v;
    }
  }
  #pragma unroll
  for (int p = 0; p < PC; p++){
    atomicAdd(&dsum[t + p * 256], (double)s[p]);
    atomicAdd(&dsq[t + p * 256], (double)q[p]);
  }
}

__global__ void bn_finalize_kernel(const double* __restrict__ dsum, const double* __restrict__ dsq,
                                   const float* __restrict__ gamma, const float* __restrict__ beta,
                                   float* __restrict__ scale, float* __restrict__ shift, int C){
  int c = blockIdx.x * blockDim.x + threadIdx.x;
  if (c < C){
    double m = dsum[c] / (double)NNODES;
    double var = dsq[c] / (double)NNODES - m * m;
    float rs = (float)(1.0 / sqrt(var + 1e-5));
    float sc = rs * gamma[c];
    scale[c] = sc;
    shift[c] = beta[c] - (float)m * sc;
  }
}

// ---------------- fused BN + softplus -> bf16 ----------------
template<int C>
__global__ void bn_softplus_kernel(const float* __restrict__ z, const float* __restrict__ scale,
                                   const float* __restrict__ shift, unsigned short* __restrict__ out,
                                   int rowsTotal){
  long i = (long)blockIdx.x * blockDim.x + threadIdx.x;
  long total = (long)rowsTotal * C / 8;
  long stride = (long)gridDim.x * blockDim.x;
  for (; i < total; i += stride){
    long e0 = i * 8;
    int c0 = (int)(e0 & (C - 1));
    const float* zp = z + e0;
    ushort8 o;
    #pragma unroll
    for (int j = 0; j < 8; j++){
      float y = fmaf(zp[j], scale[c0 + j], shift[c0 + j]);
      // stable softplus, fast intrinsics only
      float sp = fmaxf(y, 0.f) + __logf(1.f + __expf(-fabsf(y)));
      o[j] = f2bf(sp);
    }
    *(ushort8*)(out + e0) = o;
  }
}

// ---------------- bf16 MFMA GEMM: C[M][N] = A[M][K] * B[N][K]^T (+bias) -------
// 128x128 tile, BK=64, 4 waves (2x2 of 64x64), 16x16x32 bf16 MFMA.
// LDS linear dest for global_load_lds; XOR swizzle via pre-swizzled global src.
template<int EPI>
__launch_bounds__(256, 2)
__global__ void gemm_kernel(const unsigned short* __restrict__ A, const unsigned short* __restrict__ B,
                            const float* __restrict__ bias, const float* __restrict__ bias2,
                            void* __restrict__ Cout, int N, int K){
  __shared__ unsigned short As[128 * 64];
  __shared__ unsigned short Bs[128 * 64];
  const int t = threadIdx.x;
  const int lane = t & 63;
  const int w = t >> 6;
  const long row0 = (long)blockIdx.x * 128;
  const int col0 = blockIdx.y * 128;

  const int rI = lane >> 3;            // row within 8-row chunk (== row&7)
  const int sI = (lane & 7) ^ rI;      // pre-swizzled source 16B-slot

  f32x4 acc[4][4];
  #pragma unroll
  for (int i = 0; i < 4; i++)
    #pragma unroll
    for (int j = 0; j < 4; j++){
      f32x4 z = {0.f, 0.f, 0.f, 0.f};
      acc[i][j] = z;
    }

  const int wm = (w >> 1) * 64;
  const int wn = (w & 1) * 64;
  const int nk = K >> 6;

  const unsigned short* Abase = A + row0 * K + sI * 8;
  const unsigned short* Bbase = B + (long)col0 * K + sI * 8;

  for (int kt = 0; kt < nk; ++kt){
    const int kb = kt * 64;
    #pragma unroll
    for (int i = 0; i < 4; i++){
      int c = i * 4 + w;
      int rowt = c * 8 + rI;
      async16(Abase + (long)rowt * K + kb, As + c * 512);
      async16(Bbase + (long)rowt * K + kb, Bs + c * 512);
    }
    __syncthreads();
    #pragma unroll
    for (int ks = 0; ks < 2; ++ks){
      short8 af[4], bfr[4];
      #pragma unroll
      for (int f = 0; f < 4; f++){
        int ra = wm + f * 16 + (lane & 15);
        int sa = (ks * 4 + (lane >> 4)) ^ (ra & 7);
        af[f] = *(const short8*)(As + ra * 64 + sa * 8);
        int rb = wn + f * 16 + (lane & 15);
        int sb = (ks * 4 + (lane >> 4)) ^ (rb & 7);
        bfr[f] = *(const short8*)(Bs + rb * 64 + sb * 8);
      }
      #pragma unroll
      for (int fm = 0; fm < 4; fm++)
        #pragma unroll
        for (int fn = 0; fn < 4; fn++)
          acc[fm][fn] = __builtin_amdgcn_mfma_f32_16x16x32_bf16(af[fm], bfr[fn], acc[fm][fn], 0, 0, 0);
    }
    __syncthreads();
  }

  // epilogue: C/D layout col=lane&15, row=(lane>>4)*4+reg
  #pragma unroll
  for (int fm = 0; fm < 4; fm++){
    #pragma unroll
    for (int fn = 0; fn < 4; fn++){
      #pragma unroll
      for (int j = 0; j < 4; j++){
        long r = row0 + wm + fm * 16 + ((lane >> 4) * 4 + j);
        int cc = col0 + wn + fn * 16 + (lane & 15);
        float v = acc[fm][fn][j];
        if (EPI == 0){
          v += bias[cc];
          ((unsigned short*)Cout)[r * N + cc] = f2bf(v);
        } else if (EPI == 1){
          v += bias[cc];
          ((float*)Cout)[r * N + cc] = v;
        } else {
          if (r < NNODES){
            float bb = (cc < 64) ? bias[cc] : bias2[cc - 64];
            long o = (cc < 64) ? ((long)r * 64 + cc) : ((long)64 * NNODES + (long)r * 64 + (cc - 64));
            ((float*)Cout)[o] = v + bb;
          }
        }
      }
    }
  }
}

// ---------------- host ----------------
extern "C" void kernel_launch(void* const* d_in, const int* in_sizes, int n_in,
                              void* d_out, int out_size, void* d_ws, size_t ws_size,
                              hipStream_t stream){
  const float* x        = (const float*)d_in[0];
  const int*   adj_rows = (const int*)d_in[1];
  const int*   adj_cols = (const int*)d_in[2];
  const float* adj_vals = (const float*)d_in[3];
  const float* Wg       = (const float*)d_in[4];
  const float* bg       = (const float*)d_in[5];
  const float* W1       = (const float*)d_in[6];
  const float* b1       = (const float*)d_in[7];
  const float* W21      = (const float*)d_in[8];
  const float* b21      = (const float*)d_in[9];
  const float* W22      = (const float*)d_in[10];
  const float* b22      = (const float*)d_in[11];
  const float* gamma0   = (const float*)d_in[12];
  const float* beta0    = (const float*)d_in[13];
  const float* gamma1   = (const float*)d_in[14];
  const float* beta1    = (const float*)d_in[15];

  char* ws = (char*)d_ws;
  // arena
  unsigned short* xb  = (unsigned short*)(ws + 0);                 // 204,996,608 B used
  float* agg          = (float*)(ws + 0);                          // reuse after GEMM1
  float* z1           = (float*)(ws + 102498304);
  unsigned short* h1  = (unsigned short*)(ws + 153747456);
  size_t o = 205000704;
  unsigned short* WgT = (unsigned short*)(ws + o); o += 2097152;
  unsigned short* W1T = (unsigned short*)(ws + o); o += 262144;
  unsigned short* WcT = (unsigned short*)(ws + o); o += 65536;
  unsigned short* hbf = (unsigned short*)(ws + o); o += 51249152;
  unsigned short* h0  = (unsigned short*)(ws + o); o += 51249152;
  int* counts = (int*)(ws + o); o += 200192;
  int* offs   = (int*)(ws + o); o += 200192;
  int* cursor = (int*)(ws + o); o += 200192;
  unsigned long long* ep = (unsigned long long*)(ws + o); o += 12800000;
  double* dsum0 = (double*)(ws + o); o += 4096;
  double* dsq0  = (double*)(ws + o); o += 4096;
  double* dsum1 = (double*)(ws + o); o += 2048;
  double* dsq1  = (double*)(ws + o); o += 2048;
  float* scale0 = (float*)(ws + o); o += 2048;
  float* shift0 = (float*)(ws + o); o += 2048;
  float* scale1 = (float*)(ws + o); o += 1024;
  float* shift1 = (float*)(ws + o); o += 1024;
  int* part     = (int*)(ws + o); o += 1024;

  hipMemsetAsync(counts, 0, NNODES * sizeof(int), stream);
  hipMemsetAsync(dsum0, 0, 12288, stream);   // dsum0,dsq0,dsum1,dsq1 contiguous

  cast_x_kernel<<<2048, 256, 0, stream>>>(x, xb);
  prep_weights<<<1184, 256, 0, stream>>>(Wg, W1, W21, W22, WgT, W1T, WcT);

  hist_kernel<<<2048, 256, 0, stream>>>(adj_rows, counts);
  scan_partials<<<256, 256, 0, stream>>>(counts, part);
  scan_scan<<<1, 256, 0, stream>>>(part);
  scan_expand<<<256, 256, 0, stream>>>(counts, part, offs, cursor);
  fill_kernel<<<2048, 256, 0, stream>>>(adj_rows, adj_cols, adj_vals, cursor, ep);

  gemm_kernel<0><<<dim3(MPAD / 128, 4), 256, 0, stream>>>(xb, WgT, bg, nullptr, hbf, 512, 2048);

  aggregate_kernel<<<NNODES / 4, 256, 0, stream>>>(offs, ep, hbf, agg);

  bn_stats_kernel<512><<<512, 256, 0, stream>>>(agg, dsum0, dsq0);
  bn_finalize_kernel<<<2, 256, 0, stream>>>(dsum0, dsq0, gamma0, beta0, scale0, shift0, 512);
  bn_softplus_kernel<512><<<2048, 256, 0, stream>>>(agg, scale0, shift0, h0, MPAD);

  gemm_kernel<1><<<dim3(MPAD / 128, 2), 256, 0, stream>>>(h0, W1T, b1, nullptr, z1, 256, 512);

  bn_stats_kernel<256><<<512, 256, 0, stream>>>(z1, dsum1, dsq1);
  bn_finalize_kernel<<<1, 256, 0, stream>>>(dsum1, dsq1, gamma1, beta1, scale1, shift1, 256);
  bn_softplus_kernel<256><<<1024, 256, 0, stream>>>(z1, scale1, shift1, h1, MPAD);

  gemm_kernel<2><<<dim3(MPAD / 128, 1), 256, 0, stream>>>(h1, WcT, b21, b22, (float*)d_out, 128, 256);

  (void)in_sizes; (void)n_in; (void)out_size; (void)ws_size;
}